// Round 2
// baseline (383.025 us; speedup 1.0000x reference)
//
#include <hip/hip_runtime.h>

// Problem constants: B=32, T=4096, C=256, WINDOW=8, HEADS=4, hd=64
// Rows M = B*T = 131072. qkv col n = part*256 + h*64 + d.

typedef __attribute__((ext_vector_type(8))) short short8;
typedef __attribute__((ext_vector_type(4))) short short4v;
typedef __attribute__((ext_vector_type(4))) float float4v;

__device__ inline short f2bf(float f) {
  unsigned u = __builtin_bit_cast(unsigned, f);
  u = (u + 0x7FFFu + ((u >> 16) & 1u)) >> 16;   // RNE fp32 -> bf16
  return (short)u;
}

// ---- prologue: cast weights fp32 -> bf16 into workspace ----
// dst layout: [768*256] w_qkv_bf16, then [256*256] w_proj_bf16
__global__ void __launch_bounds__(256) wconv_kernel(const float* __restrict__ wqkv,
                                                    const float* __restrict__ wproj,
                                                    short* __restrict__ dst) {
  int i = blockIdx.x * 256 + threadIdx.x;          // 65536 threads, 4 elems each
  float4 v;
  if (i < 49152) v = reinterpret_cast<const float4*>(wqkv)[i];
  else           v = reinterpret_cast<const float4*>(wproj)[i - 49152];
  short4v p;
  p[0] = f2bf(v.x); p[1] = f2bf(v.y); p[2] = f2bf(v.z); p[3] = f2bf(v.w);
  reinterpret_cast<short4v*>(dst)[i] = p;
}

// ---- fused QKV + windowed attention + proj ----
__global__ void __launch_bounds__(256, 2) attn_kernel(
    const float* __restrict__ x,
    const short* __restrict__ wbf,      // bf16 weights from workspace
    const float* __restrict__ b_qkv,
    const float* __restrict__ b_proj,
    float* __restrict__ out) {

  // LDS: 64512 B total -> 2 blocks/CU
  __shared__ short sA[64 * 264];        // X tile bf16 (row-major, stride 264); later aliased as attn-out tile
  __shared__ short sQK[2 * 64 * 72];    // per-head Q,K rows [token][d], stride 72
  __shared__ short sVT[64 * 72];        // per-head V^T [d][token], stride 72
  __shared__ short sP[4 * 16 * 24];     // per-wave P tile [q][k], stride 24

  const int tid  = threadIdx.x;
  const int wv   = tid >> 6;            // wave 0..3
  const int lane = tid & 63;
  const int L    = lane & 15;
  const int quad = lane >> 4;           // 0..3
  const int bid  = blockIdx.x;

  const float4v fzero = {0.f, 0.f, 0.f, 0.f};

  // ---------- Phase 0: stage X tile (64x256 fp32 -> bf16 LDS) ----------
  // 16 iterations x 256 threads x 4 floats = 16384 floats = the full 64x256 tile.
  const float* xg = x + (size_t)bid * (64 * 256);
  #pragma unroll
  for (int i = 0; i < 16; ++i) {
    int idx = i * 1024 + tid * 4;
    float4 v = *reinterpret_cast<const float4*>(xg + idx);
    int row = idx >> 8;
    int col = idx & 255;
    short4v p;
    p[0] = f2bf(v.x); p[1] = f2bf(v.y); p[2] = f2bf(v.z); p[3] = f2bf(v.w);
    *reinterpret_cast<short4v*>(&sA[row * 264 + col]) = p;
  }
  __syncthreads();

  float oreg[4][16];                    // attention output per head: [dchunk*4 + reg]

  #pragma unroll
  for (int h = 0; h < 4; ++h) {
    // ---------- QKV GEMM: this wave computes cols [wv*48, wv*48+48) of head-local 192 ----------
    float4v acc[4][3];
    #pragma unroll
    for (int rt = 0; rt < 4; ++rt)
      #pragma unroll
      for (int ct = 0; ct < 3; ++ct) acc[rt][ct] = fzero;

    const short* wb[3];
    int s_[3], d0_[3];
    #pragma unroll
    for (int ct = 0; ct < 3; ++ct) {
      int c0 = wv * 48 + ct * 16;       // head-local col
      int s  = c0 >> 6;                 // 0=q 1=k 2=v
      int d0 = c0 & 63;
      s_[ct] = s; d0_[ct] = d0;
      int wrow0 = s * 256 + h * 64 + d0;                 // row in w_qkv
      wb[ct] = wbf + (size_t)(wrow0 + L) * 256 + quad * 8;
    }

    #pragma unroll
    for (int kk = 0; kk < 8; ++kk) {
      short8 a[4];
      #pragma unroll
      for (int rt = 0; rt < 4; ++rt)
        a[rt] = *reinterpret_cast<const short8*>(&sA[(rt * 16 + L) * 264 + kk * 32 + quad * 8]);
      short8 b[3];
      #pragma unroll
      for (int ct = 0; ct < 3; ++ct)
        b[ct] = *reinterpret_cast<const short8*>(wb[ct] + kk * 32);
      #pragma unroll
      for (int rt = 0; rt < 4; ++rt)
        #pragma unroll
        for (int ct = 0; ct < 3; ++ct)
          acc[rt][ct] = __builtin_amdgcn_mfma_f32_16x16x32_bf16(a[rt], b[ct], acc[rt][ct], 0, 0, 0);
    }

    // epilogue: + bias, scatter to sQK (row-major) / sVT (transposed)
    #pragma unroll
    for (int ct = 0; ct < 3; ++ct) {
      int s = s_[ct], d0 = d0_[ct];
      float bias = b_qkv[s * 256 + h * 64 + d0 + L];
      #pragma unroll
      for (int rt = 0; rt < 4; ++rt) {
        float4v v = acc[rt][ct];
        if (s < 2) {
          short* dst = &sQK[s * (64 * 72)];
          #pragma unroll
          for (int r = 0; r < 4; ++r)
            dst[(rt * 16 + quad * 4 + r) * 72 + d0 + L] = f2bf(v[r] + bias);
        } else {
          short4v pk;
          #pragma unroll
          for (int r = 0; r < 4; ++r) pk[r] = f2bf(v[r] + bias);
          *reinterpret_cast<short4v*>(&sVT[(d0 + L) * 72 + rt * 16 + quad * 4]) = pk;
        }
      }
    }
    __syncthreads();

    // ---------- attention: wave owns tokens [wv*16, wv*16+16) = 2 windows ----------
    float4v sacc = fzero;
    #pragma unroll
    for (int ks = 0; ks < 2; ++ks) {
      short8 qa = *reinterpret_cast<const short8*>(&sQK[(wv * 16 + L) * 72 + ks * 32 + quad * 8]);
      short8 kb = *reinterpret_cast<const short8*>(&sQK[64 * 72 + (wv * 16 + L) * 72 + ks * 32 + quad * 8]);
      sacc = __builtin_amdgcn_mfma_f32_16x16x32_bf16(qa, kb, sacc, 0, 0, 0);
    }

    // softmax in C-layout regs: row = quad*4+r (q token), col = L (k token)
    short* sPw = &sP[wv * (16 * 24)];
    #pragma unroll
    for (int r = 0; r < 4; ++r) {
      int qr = quad * 4 + r;
      bool valid = ((qr >> 3) == (L >> 3)) && ((L & 7) <= (qr & 7));  // same window + causal
      float sv = valid ? sacc[r] * 0.125f : -1e30f;
      float m = sv;
      m = fmaxf(m, __shfl_xor(m, 1));
      m = fmaxf(m, __shfl_xor(m, 2));
      m = fmaxf(m, __shfl_xor(m, 4));
      m = fmaxf(m, __shfl_xor(m, 8));
      float e = __expf(sv - m);
      float sum = e;
      sum += __shfl_xor(sum, 1);
      sum += __shfl_xor(sum, 2);
      sum += __shfl_xor(sum, 4);
      sum += __shfl_xor(sum, 8);
      sPw[qr * 24 + L] = f2bf(e / sum);
    }

    // P @ V via 16x16x32 with K zero-padded 16->32 (A=0 for quads 2,3; B token clamped)
    short8 pa = {0, 0, 0, 0, 0, 0, 0, 0};
    if (quad < 2) pa = *reinterpret_cast<const short8*>(&sPw[L * 24 + quad * 8]);
    #pragma unroll
    for (int dc = 0; dc < 4; ++dc) {
      short8 vb = *reinterpret_cast<const short8*>(
          &sVT[(dc * 16 + L) * 72 + wv * 16 + (quad & 1) * 8]);
      float4v o = __builtin_amdgcn_mfma_f32_16x16x32_bf16(pa, vb, fzero, 0, 0, 0);
      #pragma unroll
      for (int r = 0; r < 4; ++r) oreg[h][dc * 4 + r] = o[r];
    }
    __syncthreads();   // protect sQK/sVT before next head's epilogue writes
  }

  // ---------- write attention output tile into sA (X tile is dead) ----------
  #pragma unroll
  for (int h = 0; h < 4; ++h)
    #pragma unroll
    for (int dc = 0; dc < 4; ++dc)
      #pragma unroll
      for (int r = 0; r < 4; ++r)
        sA[(wv * 16 + quad * 4 + r) * 264 + h * 64 + dc * 16 + L] = f2bf(oreg[h][dc * 4 + r]);
  __syncthreads();

  // ---------- proj GEMM: wave computes cols [wv*64, wv*64+64) ----------
  float4v pacc[4][4];
  #pragma unroll
  for (int rt = 0; rt < 4; ++rt)
    #pragma unroll
    for (int ct = 0; ct < 4; ++ct) pacc[rt][ct] = fzero;

  const short* wp = wbf + 768 * 256;
  const short* wpb[4];
  #pragma unroll
  for (int ct = 0; ct < 4; ++ct)
    wpb[ct] = wp + (size_t)(wv * 64 + ct * 16 + L) * 256 + quad * 8;

  #pragma unroll
  for (int kk = 0; kk < 8; ++kk) {
    short8 a[4];
    #pragma unroll
    for (int rt = 0; rt < 4; ++rt)
      a[rt] = *reinterpret_cast<const short8*>(&sA[(rt * 16 + L) * 264 + kk * 32 + quad * 8]);
    short8 b[4];
    #pragma unroll
    for (int ct = 0; ct < 4; ++ct)
      b[ct] = *reinterpret_cast<const short8*>(wpb[ct] + kk * 32);
    #pragma unroll
    for (int rt = 0; rt < 4; ++rt)
      #pragma unroll
      for (int ct = 0; ct < 4; ++ct)
        pacc[rt][ct] = __builtin_amdgcn_mfma_f32_16x16x32_bf16(a[rt], b[ct], pacc[rt][ct], 0, 0, 0);
  }

  // epilogue: + bias, fp32 store
  float* og = out + (size_t)bid * (64 * 256);
  #pragma unroll
  for (int ct = 0; ct < 4; ++ct) {
    float bias = b_proj[wv * 64 + ct * 16 + L];
    #pragma unroll
    for (int rt = 0; rt < 4; ++rt)
      #pragma unroll
      for (int r = 0; r < 4; ++r)
        og[(rt * 16 + quad * 4 + r) * 256 + wv * 64 + ct * 16 + L] = pacc[rt][ct][r] + bias;
  }
}

extern "C" void kernel_launch(void* const* d_in, const int* in_sizes, int n_in,
                              void* d_out, int out_size, void* d_ws, size_t ws_size,
                              hipStream_t stream) {
  const float* x      = (const float*)d_in[0];
  const float* w_qkv  = (const float*)d_in[1];
  const float* b_qkv  = (const float*)d_in[2];
  const float* w_proj = (const float*)d_in[3];
  const float* b_proj = (const float*)d_in[4];
  float* out = (float*)d_out;
  short* wbf = (short*)d_ws;                      // 524288 B of bf16 weights

  wconv_kernel<<<256, 256, 0, stream>>>(w_qkv, w_proj, wbf);
  attn_kernel<<<2048, 256, 0, stream>>>(x, wbf, b_qkv, b_proj, out);
}